// Round 6
// baseline (529.582 us; speedup 1.0000x reference)
//
#include <hip/hip_runtime.h>

typedef __attribute__((ext_vector_type(8))) _Float16 f16x8;
typedef __attribute__((ext_vector_type(4))) _Float16 f16x4;
typedef __attribute__((ext_vector_type(4))) float f32x4;

#define NB 4
#define NS 4096
#define NE 512

__device__ __forceinline__ f16x8 cvt2(float4 a, float4 b) {
    f16x8 r;
    r[0] = (_Float16)a.x; r[1] = (_Float16)a.y; r[2] = (_Float16)a.z; r[3] = (_Float16)a.w;
    r[4] = (_Float16)b.x; r[5] = (_Float16)b.y; r[6] = (_Float16)b.z; r[7] = (_Float16)b.w;
    return r;
}
__device__ __forceinline__ void gload_lds16(const void* g, void* l) {
    __builtin_amdgcn_global_load_lds(
        (const __attribute__((address_space(1))) void*)g,
        (__attribute__((address_space(3))) void*)l, 16, 0, 0);
}
template <int CTRL>
__device__ __forceinline__ float dpp_mov(float x) {
    return __builtin_bit_cast(float,
        __builtin_amdgcn_mov_dpp(__builtin_bit_cast(int, x), CTRL, 0xF, 0xF, true));
}
// full 16-lane-row reductions via DPP row_ror (pure VALU, no LDS)
__device__ __forceinline__ float rowmax16(float v) {
    v = fmaxf(v, dpp_mov<0x128>(v));
    v = fmaxf(v, dpp_mov<0x124>(v));
    v = fmaxf(v, dpp_mov<0x122>(v));
    v = fmaxf(v, dpp_mov<0x121>(v));
    return v;
}
__device__ __forceinline__ float rowsum16(float v) {
    v += dpp_mov<0x128>(v);
    v += dpp_mov<0x124>(v);
    v += dpp_mov<0x122>(v);
    v += dpp_mov<0x121>(v);
    return v;
}

// ---------------- Stage 1: fused QKV projection (fp32 in, f16 out) ------
// q: natural [row][e]. k: swizzled — (s,e) at s*512 + (((e>>3)^(s&7))<<3) + (e&7).
// v: 32-key chunks [b][kc2][e][32]: (d,s) at ((b*128+kc2)*512+d)*32
//    + ((((s>>3)&3)^(d&3))<<3) + (s&7),  kc2 = (s&4095)>>5.
__global__ __launch_bounds__(256) void proj_kernel(
    const float* __restrict__ Xq, const float* __restrict__ Xk,
    const float* __restrict__ Xv,
    const float* __restrict__ Wq, const float* __restrict__ Wk,
    const float* __restrict__ Wv,
    const float* __restrict__ bq, const float* __restrict__ bk,
    const float* __restrict__ bv,
    _Float16* __restrict__ oq, _Float16* __restrict__ ok,
    _Float16* __restrict__ ovt, int b0)
{
    __shared__ __align__(16) _Float16 As[128 * 40];   // stride 40: conflict-free b128 reads
    __shared__ __align__(16) _Float16 Bs[128 * 40];
    const int t = threadIdx.x;
    const int w = t >> 6, ln = t & 63;
    const int which = blockIdx.y;
    const float* X    = (which == 0) ? Xq : ((which == 1) ? Xk : Xv);
    const float* W    = (which == 0) ? Wq : ((which == 1) ? Wk : Wv);
    const float* bias = (which == 0) ? bq : ((which == 1) ? bk : bv);

    const int m0 = (blockIdx.x >> 2) * 128;
    const int n0 = (blockIdx.x & 3) * 128;

    const int srow  = t >> 1;
    const int shalf = (t & 1) * 16;
    const float* gA = X + ((size_t)b0 * NS + m0 + srow) * NE + shalf;
    const float* gB = W + (size_t)(n0 + srow) * NE + shalf;
    _Float16* lA = &As[srow * 40 + shalf];
    _Float16* lB = &Bs[srow * 40 + shalf];

    f32x4 acc[4][4] = {};
    const int wm = (w >> 1) * 64, wn = (w & 1) * 64;
    const int lcol = ln & 15, lq = ln >> 4;

    // register double-buffer: preload k0=0
    float4 ra0 = *(const float4*)(gA),      ra1 = *(const float4*)(gA + 4);
    float4 ra2 = *(const float4*)(gA + 8),  ra3 = *(const float4*)(gA + 12);
    float4 rb0 = *(const float4*)(gB),      rb1 = *(const float4*)(gB + 4);
    float4 rb2 = *(const float4*)(gB + 8),  rb3 = *(const float4*)(gB + 12);

    for (int k0 = 0; k0 < NE; k0 += 32) {
        __syncthreads();
        *(f16x8*)lA       = cvt2(ra0, ra1);
        *(f16x8*)(lA + 8) = cvt2(ra2, ra3);
        *(f16x8*)lB       = cvt2(rb0, rb1);
        *(f16x8*)(lB + 8) = cvt2(rb2, rb3);
        __syncthreads();
        // issue next chunk's loads early (wrapped on last iter — harmless, defined)
        const int k1 = (k0 + 32) & (NE - 1);
        float4 na0 = *(const float4*)(gA + k1),      na1 = *(const float4*)(gA + k1 + 4);
        float4 na2 = *(const float4*)(gA + k1 + 8),  na3 = *(const float4*)(gA + k1 + 12);
        float4 nb0 = *(const float4*)(gB + k1),      nb1 = *(const float4*)(gB + k1 + 4);
        float4 nb2 = *(const float4*)(gB + k1 + 8),  nb3 = *(const float4*)(gB + k1 + 12);

        f16x8 a[4], b[4];
#pragma unroll
        for (int i = 0; i < 4; i++)
            a[i] = *(const f16x8*)&As[(wm + i * 16 + lcol) * 40 + lq * 8];
#pragma unroll
        for (int j = 0; j < 4; j++)
            b[j] = *(const f16x8*)&Bs[(wn + j * 16 + lcol) * 40 + lq * 8];
#pragma unroll
        for (int i = 0; i < 4; i++)
#pragma unroll
            for (int j = 0; j < 4; j++)
                acc[i][j] = __builtin_amdgcn_mfma_f32_16x16x32_f16(a[i], b[j], acc[i][j], 0, 0, 0);

        ra0 = na0; ra1 = na1; ra2 = na2; ra3 = na3;
        rb0 = nb0; rb1 = nb1; rb2 = nb2; rb3 = nb3;
    }

    // C/D layout: col = lane&15, row = (lane>>4)*4 + reg
    if (which == 0) {
#pragma unroll
        for (int j = 0; j < 4; j++) {
            const int col = n0 + wn + j * 16 + lcol;
            const float bb = bias[col];
#pragma unroll
            for (int i = 0; i < 4; i++) {
                const int rbase = m0 + wm + i * 16 + lq * 4;
#pragma unroll
                for (int r = 0; r < 4; r++)
                    oq[(size_t)(rbase + r) * NE + col] = (_Float16)(acc[i][j][r] + bb);
            }
        }
    } else if (which == 1) {
#pragma unroll
        for (int j = 0; j < 4; j++) {
            const int col = n0 + wn + j * 16 + lcol;
            const int cch = col >> 3, clo = col & 7;
            const float bb = bias[col];
#pragma unroll
            for (int i = 0; i < 4; i++) {
                const int rbase = m0 + wm + i * 16 + lq * 4;
#pragma unroll
                for (int r = 0; r < 4; r++) {
                    const int s = rbase + r;
                    ok[(size_t)s * NE + ((cch ^ (s & 7)) << 3) + clo] =
                        (_Float16)(acc[i][j][r] + bb);
                }
            }
        }
    } else {
#pragma unroll
        for (int j = 0; j < 4; j++) {
            const int d = n0 + wn + j * 16 + lcol;
            const float bb = bias[d];
#pragma unroll
            for (int i = 0; i < 4; i++) {
                const int rbase = m0 + wm + i * 16 + lq * 4;
                const int bat = rbase >> 12;
                const int sl  = rbase & 4095;
                const int kc2 = sl >> 5;
                const int slot = ((sl >> 3) & 3) ^ (d & 3);
                f16x4 pk;
#pragma unroll
                for (int r = 0; r < 4; r++) pk[r] = (_Float16)(acc[i][j][r] + bb);
                *(f16x4*)&ovt[(((size_t)bat * 128 + kc2) * NE + d) * 32 + slot * 8 + (sl & 7)] = pk;
            }
        }
    }
}

// ---------------- Stage 2: flash attention v6 ---------------------------
// 512 thr = 8 waves; 64 q-rows, BK=32, double-buffered K/V DMA (exposure ~0).
// wave (rt=w&3, g=w>>2): QK keys [g*16,g*16+16), PV E-half [g*256,g*256+256).
__global__ __launch_bounds__(512, 2) void attn_kernel(
    const _Float16* __restrict__ q, const _Float16* __restrict__ ksw,
    const _Float16* __restrict__ vsw, float* __restrict__ out, int b0)
{
    __shared__ __align__(16) _Float16 Kbuf[2][32 * 512];   // 2 x 32 KB
    __shared__ __align__(16) _Float16 Vbuf[2][512 * 32];   // 2 x 32 KB
    __shared__ __align__(16) _Float16 Pb[64 * 40];
    __shared__ float mpart[2][64];
    __shared__ float lpart[2][64];

    const int t = threadIdx.x, w = t >> 6, ln = t & 63;
    const int lcol = ln & 15, lq = ln >> 4;
    const int rt = w & 3, g = w >> 2;
    const int xm = lcol & 7;
    const int rel = blockIdx.y, babs = b0 + rel;
    const int q0 = blockIdx.x * 64;

    const _Float16* qp = q + ((size_t)rel * NS + q0 + rt * 16 + lcol) * NE + lq * 8;
    f16x8 qf[16];
#pragma unroll
    for (int ks = 0; ks < 16; ks++) qf[ks] = *(const f16x8*)(qp + ks * 32);

    const _Float16* kbase = ksw + (size_t)rel * NS * NE;
    const _Float16* vbase = vsw + (size_t)rel * NS * NE;

    // prologue: DMA chunk 0 into buffer 0
#pragma unroll
    for (int i = 0; i < 4; i++) {
        const int blk = i * 8 + w;
        gload_lds16(kbase + (size_t)blk * 512 + ln * 8, &Kbuf[0][blk * 512]);
        gload_lds16(vbase + (size_t)blk * 512 + ln * 8, &Vbuf[0][blk * 512]);
    }

    f32x4 oacc[16] = {};
    float m_st[4] = {-1e30f, -1e30f, -1e30f, -1e30f};
    float l_st[4] = {0.f, 0.f, 0.f, 0.f};

    for (int kc = 0; kc < 128; kc++) {
        const int p = kc & 1;
        __syncthreads();            // joins + drains DMA[kc] (issued one iter ago)
        if (kc + 1 < 128) {         // issue DMA[kc+1] into the idle buffer
            const _Float16* kn = kbase + (size_t)(kc + 1) * 32 * 512;
            const _Float16* vn = vbase + (size_t)(kc + 1) * 512 * 32;
#pragma unroll
            for (int i = 0; i < 4; i++) {
                const int blk = i * 8 + w;
                gload_lds16(kn + (size_t)blk * 512 + ln * 8, &Kbuf[1 - p][blk * 512]);
                gload_lds16(vn + (size_t)blk * 512 + ln * 8, &Vbuf[1 - p][blk * 512]);
            }
        }

        // QK: 16 rows x 16 keys (keys g*16..+16)
        f32x4 s0 = {};
#pragma unroll
        for (int ks = 0; ks < 16; ks++) {
            f16x8 kb = *(const f16x8*)&Kbuf[p][(g * 16 + lcol) * 512 + (((ks * 4 + lq) ^ xm) << 3)];
            s0 = __builtin_amdgcn_mfma_f32_16x16x32_f16(qf[ks], kb, s0, 0, 0, 0);
        }
        // partial row-max via DPP
#pragma unroll
        for (int r = 0; r < 4; r++) {
            float vmx = rowmax16(s0[r]);
            if (lcol == 0) mpart[g][rt * 16 + lq * 4 + r] = vmx;
        }
        __syncthreads();            // S2: mpart visible

        float alpha[4];
#pragma unroll
        for (int r = 0; r < 4; r++) {
            const int row = rt * 16 + lq * 4 + r;
            float mc = fmaxf(mpart[0][row], mpart[1][row]);
            float mn = fmaxf(m_st[r], mc);
            alpha[r] = __expf(m_st[r] - mn);
            float pv = __expf(s0[r] - mn);
            Pb[row * 40 + g * 16 + lcol] = (_Float16)pv;
            float sm = rowsum16(pv);
            if (lcol == 0) lpart[g][row] = sm;
            m_st[r] = mn;
        }
        __syncthreads();            // S3: Pb + lpart visible
#pragma unroll
        for (int r = 0; r < 4; r++) {
            const int row = rt * 16 + lq * 4 + r;
            l_st[r] = l_st[r] * alpha[r] + lpart[0][row] + lpart[1][row];
        }
        bool allone = (alpha[0] == 1.f) & (alpha[1] == 1.f) &
                      (alpha[2] == 1.f) & (alpha[3] == 1.f);
        if (!__all(allone)) {
#pragma unroll
            for (int et = 0; et < 16; et++) {
                oacc[et][0] *= alpha[0]; oacc[et][1] *= alpha[1];
                oacc[et][2] *= alpha[2]; oacc[et][3] *= alpha[3];
            }
        }
        // PV: rows rt*16..+16 x E-cols g*256..+256, K=32
        f16x8 pa = *(const f16x8*)&Pb[(rt * 16 + lcol) * 40 + lq * 8];
#pragma unroll
        for (int et = 0; et < 16; et++) {
            const int e = g * 256 + et * 16 + lcol;
            f16x8 vb = *(const f16x8*)&Vbuf[p][e * 32 + ((lq ^ (e & 3)) << 3)];
            oacc[et] = __builtin_amdgcn_mfma_f32_16x16x32_f16(pa, vb, oacc[et], 0, 0, 0);
        }
    }

#pragma unroll
    for (int r = 0; r < 4; r++) {
        const float inv = 1.0f / l_st[r];
        const size_t ob = ((size_t)babs * NS + q0 + rt * 16 + lq * 4 + r) * NE + g * 256 + lcol;
#pragma unroll
        for (int et = 0; et < 16; et++)
            out[ob + et * 16] = oacc[et][r] * inv;
    }
}

extern "C" void kernel_launch(void* const* d_in, const int* in_sizes, int n_in,
                              void* d_out, int out_size, void* d_ws, size_t ws_size,
                              hipStream_t stream) {
    const float* query = (const float*)d_in[0];
    const float* key_  = (const float*)d_in[1];
    const float* value = (const float*)d_in[2];
    const float* Wq    = (const float*)d_in[3];
    const float* bq    = (const float*)d_in[4];
    const float* Wk    = (const float*)d_in[5];
    const float* bk    = (const float*)d_in[6];
    const float* Wv    = (const float*)d_in[7];
    const float* bv    = (const float*)d_in[8];

    const size_t per_batch = (size_t)3 * NS * NE * 2;   // q + k_sw + v_sw f16 = 12 MiB
    int nb_chunk = (int)(ws_size / per_batch);
    if (nb_chunk > NB) nb_chunk = NB;
    if (nb_chunk < 1)  nb_chunk = 1;

    _Float16* qh  = (_Float16*)d_ws;
    _Float16* kh  = qh + (size_t)nb_chunk * NS * NE;
    _Float16* vth = kh + (size_t)nb_chunk * NS * NE;

    for (int b0 = 0; b0 < NB; b0 += nb_chunk) {
        int nb = NB - b0 < nb_chunk ? NB - b0 : nb_chunk;
        proj_kernel<<<dim3(nb * 128, 3, 1), 256, 0, stream>>>(
            query, key_, value, Wq, Wk, Wv, bq, bk, bv, qh, kh, vth, b0);
        attn_kernel<<<dim3(NS / 64, nb, 1), 512, 0, stream>>>(
            qh, kh, vth, (float*)d_out, b0);
    }
}